// Round 3
// baseline (5626.705 us; speedup 1.0000x reference)
//
#include <hip/hip_runtime.h>

// ---------------------------------------------------------------------------
// 3-layer SimpleRNN, B=256 T=512 U=512 E=128, fp16 MFMA.
// R8 = R7 design, R6 structure (generic-lambda removed; it broke hipcc's
// asm-operand capture).
//  - bid remap: mg = bid&7 -> each mgroup's 12 blocks (3 layers x 4 strips)
//    share bid%8 -> same XCD under round-robin dispatch.
//  - runtime handshake verifies colocation via s_getreg(HW_REG_XCC_ID);
//    verified groups use sc0-only exchange (shared per-XCD L2 = coherence
//    point) instead of sc0 sc1 (LLC/HBM path). Decision is group-consistent
//    (all 12 blocks compute it from the same 12 published ids).
//  - tagged dwords (tag<<16 | fp16) self-validate: no producer drain, no
//    flag publish on the critical path, no poll RT. Retries monotonic-sound.
//  - NON-speculative issue (R6 lesson: speculation at end-of-step is
//    guaranteed stale -> 2 full-payload coherent rounds per step).
// ---------------------------------------------------------------------------

#define BATCH 256
#define SEQ   512
#define EMBD  128
#define UNIT  512

typedef _Float16 half8 __attribute__((ext_vector_type(8)));
typedef _Float16 half4 __attribute__((ext_vector_type(4)));
typedef float    f32x4 __attribute__((ext_vector_type(4)));
typedef unsigned int uint4v __attribute__((ext_vector_type(4)));
typedef unsigned int uint2v __attribute__((ext_vector_type(2)));

// ws layout (bytes). Ring holds tagged dwords: slot = 32 rows x 512 dwords.
#define FLAGS_BYTES 4096
#define HBUF_OFF    4096
#define SLOT_BYTES  65536                      // 32*512*4
#define HBUF_BYTES  (3*8*4*SLOT_BYTES)         // 6 MB
#define PWX0_OFF    (HBUF_OFF + HBUF_BYTES)
#define PWH0_OFF    (PWX0_OFF + EMBD*UNIT*2)
#define PWX1_OFF    (PWH0_OFF + UNIT*UNIT*2)
#define PWH1_OFF    (PWX1_OFF + UNIT*UNIT*2)

// ---------------------------------------------------------------------------
__device__ __forceinline__ void sc_st_int(int* p, int v) {   // device-coherent
    asm volatile("global_store_dword %0, %1, off sc0 sc1" :: "v"(p), "v"(v) : "memory");
}
__device__ __forceinline__ unsigned hbits(_Float16 h) {
    union { _Float16 f; unsigned short u; } x; x.f = h; return (unsigned)x.u;
}

// ---------------------------------------------------------------------------
__global__ void fill_ws_kernel(uint4v* __restrict__ p, int n16, unsigned pat) {
    int i = blockIdx.x * 256 + threadIdx.x;
    uint4v z = {pat, pat, pat, pat};
    if (i < n16) p[i] = z;
}

// Pack fp32 weight [K][N] into MFMA B-fragment order, fp16:
__global__ void pack_w_kernel(const float* __restrict__ src, _Float16* __restrict__ dst,
                              int K, int N) {
    int idx = blockIdx.x * 256 + threadIdx.x;
    if (idx >= K * N) return;
    int j    = idx & 7;
    int lane = (idx >> 3) & 63;
    int rest = idx >> 9;
    int KT   = K >> 5;
    int kt   = rest % KT;
    int nt   = rest / KT;
    int k = kt*32 + (lane >> 4)*8 + j;
    int n = nt*16 + (lane & 15);
    dst[idx] = (_Float16)src[k * N + n];
}

// ---------------------------------------------------------------------------
// exchange asm clauses, parameterized by cache-bit string (expand in scope)
#define LD12(SC) asm volatile(                                  \
    "global_load_dwordx4 %0,  %12, %16 " SC "\n\t"              \
    "global_load_dwordx4 %1,  %13, %16 " SC "\n\t"              \
    "global_load_dwordx4 %2,  %14, %16 " SC "\n\t"              \
    "global_load_dwordx4 %3,  %15, %16 " SC "\n\t"              \
    "global_load_dwordx4 %4,  %12, %17 " SC "\n\t"              \
    "global_load_dwordx4 %5,  %13, %17 " SC "\n\t"              \
    "global_load_dwordx4 %6,  %14, %17 " SC "\n\t"              \
    "global_load_dwordx4 %7,  %15, %17 " SC "\n\t"              \
    "global_load_dwordx4 %8,  %12, %18 " SC "\n\t"              \
    "global_load_dwordx4 %9,  %13, %18 " SC "\n\t"              \
    "global_load_dwordx4 %10, %14, %18 " SC "\n\t"              \
    "global_load_dwordx4 %11, %15, %18 " SC                     \
    : "=&v"(s0),"=&v"(s1),"=&v"(s2),"=&v"(s3),"=&v"(s4),"=&v"(s5),  \
      "=&v"(s6),"=&v"(s7),"=&v"(s8),"=&v"(s9),"=&v"(s10),"=&v"(s11) \
    : "v"(vsf0),"v"(vsf1),"v"(vsf2),"v"(vsf3),"s"(bA),"s"(bB),"s"(bC) \
    : "memory")

#define LDFQ(SC) asm volatile("global_load_dwordx4 %0, %1, off " SC \
    : "=&v"(fq) : "v"(qDn) : "memory")

#define LD8A(SC) asm volatile(                                  \
    "global_load_dwordx4 %0, %8,  %12 " SC "\n\t"               \
    "global_load_dwordx4 %1, %9,  %12 " SC "\n\t"               \
    "global_load_dwordx4 %2, %10, %12 " SC "\n\t"               \
    "global_load_dwordx4 %3, %11, %12 " SC "\n\t"               \
    "global_load_dwordx4 %4, %8,  %13 " SC "\n\t"               \
    "global_load_dwordx4 %5, %9,  %13 " SC "\n\t"               \
    "global_load_dwordx4 %6, %10, %13 " SC "\n\t"               \
    "global_load_dwordx4 %7, %11, %13 " SC                      \
    : "=&v"(a0),"=&v"(a1),"=&v"(a2),"=&v"(a3),                  \
      "=&v"(a4),"=&v"(a5),"=&v"(a6),"=&v"(a7)                   \
    : "v"(vaf0),"v"(vaf1),"v"(vaf2),"v"(vaf3),"s"(ab),"s"(ab + 16384) \
    : "memory")

#define LD8B(SC) asm volatile(                                  \
    "global_load_dwordx4 %0, %8,  %12 " SC "\n\t"               \
    "global_load_dwordx4 %1, %9,  %12 " SC "\n\t"               \
    "global_load_dwordx4 %2, %10, %12 " SC "\n\t"               \
    "global_load_dwordx4 %3, %11, %12 " SC "\n\t"               \
    "global_load_dwordx4 %4, %8,  %13 " SC "\n\t"               \
    "global_load_dwordx4 %5, %9,  %13 " SC "\n\t"               \
    "global_load_dwordx4 %6, %10, %13 " SC "\n\t"               \
    "global_load_dwordx4 %7, %11, %13 " SC                      \
    : "=&v"(a8),"=&v"(a9),"=&v"(a10),"=&v"(a11),                \
      "=&v"(a12),"=&v"(a13),"=&v"(a14),"=&v"(a15)               \
    : "v"(vaf0),"v"(vaf1),"v"(vaf2),"v"(vaf3),"s"(ab + 32768),"s"(ab + 49152) \
    : "memory")

#define ST4(SC) asm volatile(                                   \
    "global_store_dwordx4 %4, %0, %5 " SC "\n\t"                \
    "global_store_dwordx4 %4, %1, %5 offset:16 " SC "\n\t"      \
    "global_store_dwordx4 %4, %2, %5 offset:32 " SC "\n\t"      \
    "global_store_dwordx4 %4, %3, %5 offset:48 " SC             \
    :: "v"(sv0),"v"(sv1),"v"(sv2),"v"(sv3),"v"(voff_st),"s"(stb) \
    : "memory")

// stage one sibling quad (4 tagged dwords = 4 halfs, cols ch0..ch0+3) into Ah
#define STAGE_SIB(Q, CS, II) do {                                              \
    int r_   = (II)*8 + (tid >> 5);                                            \
    int ch0_ = (CS) + (tid & 31)*4;                                            \
    unsigned lo_ = ((Q)[0] & 0xFFFFu) | ((Q)[1] << 16);                        \
    unsigned hi_ = ((Q)[2] & 0xFFFFu) | ((Q)[3] << 16);                        \
    *(uint2v*)((unsigned*)&Ah[r_][0] +                                         \
        ((((ch0_ >> 3) + r_) & 63)*4 + ((ch0_ >> 2) & 1)*2)) = (uint2v){lo_, hi_}; \
} while (0)

#define STAGE_AIN(Q, II) do {                                                  \
    int m_  = (II)*256 + tid;                                                  \
    int r_  = m_ >> 7;                                                         \
    int cg_ = m_ & 127;                                                        \
    unsigned lo_ = ((Q)[0] & 0xFFFFu) | ((Q)[1] << 16);                        \
    unsigned hi_ = ((Q)[2] & 0xFFFFu) | ((Q)[3] << 16);                        \
    *(uint2v*)((unsigned*)&Ain[r_][0] +                                        \
        ((((cg_ >> 1) + r_) & 63)*4 + (cg_ & 1)*2)) = (uint2v){lo_, hi_};      \
} while (0)

// ---------------------------------------------------------------------------
__global__ __launch_bounds__(256, 1)
void rnn_main_kernel(const int*   __restrict__ tokens,
                     const float* __restrict__ emb,
                     const float* __restrict__ b0,
                     const float* __restrict__ b1,
                     char* ws)
{
    const int bid   = blockIdx.x;
    const int mg    = bid & 7;           // batch group -> XCD under round-robin
    const int inner = bid >> 3;          // 0..11
    const int layer = inner >> 2;        // 0..2
    const int ns    = inner & 3;         // N-strip (128 cols)
    const int tid   = threadIdx.x;
    const int wv    = tid >> 6;
    const int lane  = tid & 63;
    const int q     = lane >> 4;
    const int c16   = lane & 15;

    int* flags  = (int*)ws;
    int* qDn    = flags + ((layer < 2 ? layer + 1 : layer)*8 + mg)*32;
    int* myCons = flags + (layer*8 + mg)*32 + ns;
    int* xslots = flags + 768;           // 96 ints: per-block XCD id + 1

    char* hbuf = ws + HBUF_OFF;
    const _Float16* pWh = (const _Float16*)(ws + (layer == 0 ? PWH0_OFF : PWH1_OFF));
    const _Float16* pWx = (const _Float16*)(ws + (layer == 0 ? PWX0_OFF : PWX1_OFF));
    const float* bias = (layer == 0) ? b0 : b1;

    const int c0  = ns*128 + wv*32;      // global col base of this wave
    const int nt0 = c0 >> 4;
    const int m0  = mg * 32;
    const int bc0 = ns * 128;

    const int sA = (ns == 0) ? 1 : 0;
    const int sB = (ns <= 1) ? 2 : 1;
    const int sC = (ns <= 2) ? 3 : 2;
    const int CsA = sA*128, CsB = sB*128, CsC = sC*128;

    __shared__ __align__(16) _Float16 Ah [32][512];
    __shared__ __align__(16) _Float16 Ain[32][512];
    __shared__ __align__(16) unsigned Bounce[32][128];   // tagged dwords
    __shared__ int wflag[4];
    __shared__ int fastsh;

    // ---- XCD colocation handshake (tid 0): publish id, check 12 group members
    if (tid == 0) {
        unsigned xcc;
        asm volatile("s_getreg_b32 %0, hwreg(HW_REG_XCC_ID)" : "=s"(xcc));
        sc_st_int(xslots + bid, (int)(xcc & 0xFu) + 1);
        int id0 = 0; bool same = true;
        for (int i = 0; i < 12; ++i) {
            int v;
            for (;;) {
                asm volatile("global_load_dword %0, %1, off sc0 sc1\n\ts_waitcnt vmcnt(0)"
                             : "=v"(v) : "v"(xslots + (mg + 8*i)) : "memory");
                if (v != 0) break;
                __builtin_amdgcn_s_sleep(1);
            }
            if (i == 0) id0 = v; else same = same && (v == id0);
        }
        fastsh = same ? 1 : 0;
    }

    // zero Ah: h(-1) = 0 (own strip; sibling cols staged from prefilled ring)
    {
        uint4v z = {0u,0u,0u,0u};
#pragma unroll
        for (int i = 0; i < 8; ++i) ((uint4v*)Ah)[i*256 + tid] = z;
    }

    // ---- register-resident weights (B-fragments) ----
    half8 whf[16][2];
    half8 wxf[16][2];
#pragma unroll
    for (int kt = 0; kt < 16; ++kt)
#pragma unroll
        for (int n = 0; n < 2; ++n)
            whf[kt][n] = *(const half8*)&pWh[(((nt0 + n)*16 + kt)*64 + lane) * 8];
    if (layer == 0) {
#pragma unroll
        for (int kt = 0; kt < 4; ++kt)
#pragma unroll
            for (int n = 0; n < 2; ++n)
                wxf[kt][n] = *(const half8*)&pWx[(((nt0 + n)*4 + kt)*64 + lane) * 8];
    } else {
#pragma unroll
        for (int kt = 0; kt < 16; ++kt)
#pragma unroll
            for (int n = 0; n < 2; ++n)
                wxf[kt][n] = *(const half8*)&pWx[(((nt0 + n)*16 + kt)*64 + lane) * 8];
    }

    const float bv0 = bias[c0 + c16];
    const float bv1 = bias[c0 + 16 + c16];

    // per-thread voffsets for the exchange clauses
    const unsigned voff_sib = ((unsigned)(tid >> 5))*2048u + ((unsigned)(tid & 31))*16u;
    const unsigned vsf0 = voff_sib, vsf1 = voff_sib + 16384u,
                   vsf2 = voff_sib + 32768u, vsf3 = voff_sib + 49152u;
    const unsigned vaf0 = (unsigned)tid*16u, vaf1 = vaf0 + 4096u,
                   vaf2 = vaf0 + 8192u, vaf3 = vaf0 + 12288u;
    const unsigned voff_st = ((unsigned)(tid >> 3))*2048u + ((unsigned)(tid & 7))*64u;

    __syncthreads();                     // fastsh ready (+ Ah zero done)
    const bool fastp = (fastsh != 0);

    // exchange clause registers
    uint4v s0,s1,s2,s3,s4,s5,s6,s7,s8,s9,s10,s11;               // sibling quads
    uint4v a0,a1,a2,a3,a4,a5,a6,a7,a8,a9,a10,a11,a12,a13,a14,a15; // Ain quads
    uint4v fq;                                                   // consumed quad
    uint4v sv0 = {0,0,0,0}, sv1 = {0,0,0,0}, sv2 = {0,0,0,0}, sv3 = {0,0,0,0};

    auto issue_all = [&](int tt) {
        {
            const char* sb = hbuf + (size_t)((layer*8 + mg)*4 + ((tt + 3) & 3)) * SLOT_BYTES;
            const char* bA = sb + CsA*4;
            const char* bB = sb + CsB*4;
            const char* bC = sb + CsC*4;
            if (fastp) { LD12("sc0"); LDFQ("sc0"); }
            else       { LD12("sc0 sc1"); LDFQ("sc0 sc1"); }
        }
        if (layer > 0) {
            const char* ab = hbuf + (size_t)(((layer - 1)*8 + mg)*4 + (tt & 3)) * SLOT_BYTES;
            if (fastp) { LD8A("sc0"); LD8B("sc0"); }
            else       { LD8A("sc0 sc1"); LD8B("sc0 sc1"); }
        }
    };

    for (int t = 0; t < SEQ; ++t) {
        const unsigned exps = ((unsigned)((t - 1) & 0xFFFF)) << 16;  // sibling tag
        const unsigned expa = ((unsigned)( t      & 0xFFFF)) << 16;  // up-layer tag
        const uint4v exps4 = {exps, exps, exps, exps};
        const uint4v expa4 = {expa, expa, expa, expa};

        issue_all(t);                // non-speculative: issue at point of need

        // ---- validate exchange data (retry-reload on staleness) ----
        for (;;) {
            asm volatile("s_waitcnt vmcnt(0)"
                : "+v"(s0),"+v"(s1),"+v"(s2),"+v"(s3),"+v"(s4),"+v"(s5),
                  "+v"(s6),"+v"(s7),"+v"(s8),"+v"(s9),"+v"(s10),"+v"(s11)
                : "v"(sv0),"v"(sv1),"v"(sv2),"v"(sv3)
                : "memory");
            if (layer > 0) {
                asm volatile("" : "+v"(a0),"+v"(a1),"+v"(a2),"+v"(a3),
                                  "+v"(a4),"+v"(a5),"+v"(a6),"+v"(a7) :: "memory");
                asm volatile("" : "+v"(a8),"+v"(a9),"+v"(a10),"+v"(a11),
                                  "+v"(a12),"+v"(a13),"+v"(a14),"+v"(a15),"+v"(fq) :: "memory");
            } else {
                asm volatile("" : "+v"(fq) :: "memory");
            }

            uint4v badv = {0u,0u,0u,0u};
            badv |= (s0 ^ exps4);  badv |= (s1 ^ exps4);  badv |= (s2  ^ exps4);
            badv |= (s3 ^ exps4);  badv |= (s4 ^ exps4);  badv |= (s5  ^ exps4);
            badv |= (s6 ^ exps4);  badv |= (s7 ^ exps4);  badv |= (s8  ^ exps4);
            badv |= (s9 ^ exps4);  badv |= (s10 ^ exps4); badv |= (s11 ^ exps4);
            if (layer > 0) {
                badv |= (a0  ^ expa4); badv |= (a1  ^ expa4); badv |= (a2  ^ expa4);
                badv |= (a3  ^ expa4); badv |= (a4  ^ expa4); badv |= (a5  ^ expa4);
                badv |= (a6  ^ expa4); badv |= (a7  ^ expa4); badv |= (a8  ^ expa4);
                badv |= (a9  ^ expa4); badv |= (a10 ^ expa4); badv |= (a11 ^ expa4);
                badv |= (a12 ^ expa4); badv |= (a13 ^ expa4); badv |= (a14 ^ expa4);
                badv |= (a15 ^ expa4);
            }
            unsigned bad = (badv[0] | badv[1] | badv[2] | badv[3]) & 0xFFFF0000u;
            if (layer < 2) {   // ring-reuse: down layer secured step t-4 of our slot
                int mn = (int)fq[0];
                mn = ((int)fq[1] < mn) ? (int)fq[1] : mn;
                mn = ((int)fq[2] < mn) ? (int)fq[2] : mn;
                mn = ((int)fq[3] < mn) ? (int)fq[3] : mn;
                if (mn < t - 3) bad |= 1u;
            }
            unsigned long long wb = __ballot(bad != 0u);
            if (lane == 0) wflag[wv] = (wb != 0ull) ? 1 : 0;
            __syncthreads();
            int any = wflag[0] | wflag[1] | wflag[2] | wflag[3];
            __syncthreads();
            if (!any) break;
            issue_all(t);
        }

        // our input loads retired -> up layer may reuse its ring slot
        if (layer > 0 && tid == 0) {
            if (fastp)
                asm volatile("global_store_dword %0, %1, off sc0" :: "v"(myCons), "v"(t + 1) : "memory");
            else
                asm volatile("global_store_dword %0, %1, off sc0 sc1" :: "v"(myCons), "v"(t + 1) : "memory");
        }

        // ---- stage siblings -> Ah ----
        STAGE_SIB(s0, CsA, 0); STAGE_SIB(s1, CsA, 1); STAGE_SIB(s2,  CsA, 2); STAGE_SIB(s3,  CsA, 3);
        STAGE_SIB(s4, CsB, 0); STAGE_SIB(s5, CsB, 1); STAGE_SIB(s6,  CsB, 2); STAGE_SIB(s7,  CsB, 3);
        STAGE_SIB(s8, CsC, 0); STAGE_SIB(s9, CsC, 1); STAGE_SIB(s10, CsC, 2); STAGE_SIB(s11, CsC, 3);

        if (layer > 0) {
            STAGE_AIN(a0, 0);  STAGE_AIN(a1, 1);  STAGE_AIN(a2, 2);  STAGE_AIN(a3, 3);
            STAGE_AIN(a4, 4);  STAGE_AIN(a5, 5);  STAGE_AIN(a6, 6);  STAGE_AIN(a7, 7);
            STAGE_AIN(a8, 8);  STAGE_AIN(a9, 9);  STAGE_AIN(a10,10); STAGE_AIN(a11,11);
            STAGE_AIN(a12,12); STAGE_AIN(a13,13); STAGE_AIN(a14,14); STAGE_AIN(a15,15);
        } else {
            // layer 0: embedding gather (plain cached loads)
#pragma unroll
            for (int i = 0; i < 4; ++i) {
                int idx = i*256 + tid;
                int r   = idx >> 5;
                int qq  = idx & 31;
                int tok = tokens[(m0 + r)*SEQ + t];
                float4 f = *((const float4*)(emb + (long)tok * EMBD) + qq);
                half4 h = { (_Float16)f.x, (_Float16)f.y, (_Float16)f.z, (_Float16)f.w };
                *(half4*)&Ain[r][((((qq >> 1) + r) & 63) * 8) + (qq & 1) * 4] = h;
            }
        }
        __syncthreads();   // (C1) Ah + Ain ready

        f32x4 acc00 = {0,0,0,0}, acc01 = {0,0,0,0}, acc10 = {0,0,0,0}, acc11 = {0,0,0,0};

#pragma unroll
        for (int kt = 0; kt < 16; ++kt) {
            half8 fa0 = *(const half8*)&Ah[c16]     [((kt*4 + q + c16)      & 63) * 8];
            half8 fa1 = *(const half8*)&Ah[16 + c16][((kt*4 + q + 16 + c16) & 63) * 8];
            acc00 = __builtin_amdgcn_mfma_f32_16x16x32_f16(fa0, whf[kt][0], acc00, 0, 0, 0);
            acc01 = __builtin_amdgcn_mfma_f32_16x16x32_f16(fa0, whf[kt][1], acc01, 0, 0, 0);
            acc10 = __builtin_amdgcn_mfma_f32_16x16x32_f16(fa1, whf[kt][0], acc10, 0, 0, 0);
            acc11 = __builtin_amdgcn_mfma_f32_16x16x32_f16(fa1, whf[kt][1], acc11, 0, 0, 0);
        }
        if (layer > 0) {
#pragma unroll
            for (int kt = 0; kt < 16; ++kt) {
                half8 fa0 = *(const half8*)&Ain[c16]     [((kt*4 + q + c16)      & 63) * 8];
                half8 fa1 = *(const half8*)&Ain[16 + c16][((kt*4 + q + 16 + c16) & 63) * 8];
                acc00 = __builtin_amdgcn_mfma_f32_16x16x32_f16(fa0, wxf[kt][0], acc00, 0, 0, 0);
                acc01 = __builtin_amdgcn_mfma_f32_16x16x32_f16(fa0, wxf[kt][1], acc01, 0, 0, 0);
                acc10 = __builtin_amdgcn_mfma_f32_16x16x32_f16(fa1, wxf[kt][0], acc10, 0, 0, 0);
                acc11 = __builtin_amdgcn_mfma_f32_16x16x32_f16(fa1, wxf[kt][1], acc11, 0, 0, 0);
            }
        } else {
#pragma unroll
            for (int kt = 0; kt < 4; ++kt) {
                half8 fa0 = *(const half8*)&Ain[c16]     [((kt*4 + q + c16)      & 63) * 8];
                half8 fa1 = *(const half8*)&Ain[16 + c16][((kt*4 + q + 16 + c16) & 63) * 8];
                acc00 = __builtin_amdgcn_mfma_f32_16x16x32_f16(fa0, wxf[kt][0], acc00, 0, 0, 0);
                acc01 = __builtin_amdgcn_mfma_f32_16x16x32_f16(fa0, wxf[kt][1], acc01, 0, 0, 0);
                acc10 = __builtin_amdgcn_mfma_f32_16x16x32_f16(fa1, wxf[kt][0], acc10, 0, 0, 0);
                acc11 = __builtin_amdgcn_mfma_f32_16x16x32_f16(fa1, wxf[kt][1], acc11, 0, 0, 0);
            }
        }

        // ---- tanh -> hv regs + tagged Bounce ----
        const unsigned tagw = ((unsigned)t) << 16;
        _Float16 hv[16];
#pragma unroll
        for (int r = 0; r < 4; ++r) {
            int row0 = q*4 + r, row1 = 16 + row0;
            float z, e; _Float16 v;
            z = acc00[r] + bv0; e = __expf(2.0f*z); v = (_Float16)(1.0f - 2.0f/(e + 1.0f));
            hv[r*4+0] = v; Bounce[row0][wv*32 + c16]      = tagw | hbits(v);
            z = acc01[r] + bv1; e = __expf(2.0f*z); v = (_Float16)(1.0f - 2.0f/(e + 1.0f));
            hv[r*4+1] = v; Bounce[row0][wv*32 + 16 + c16] = tagw | hbits(v);
            z = acc10[r] + bv0; e = __expf(2.0f*z); v = (_Float16)(1.0f - 2.0f/(e + 1.0f));
            hv[r*4+2] = v; Bounce[row1][wv*32 + c16]      = tagw | hbits(v);
            z = acc11[r] + bv1; e = __expf(2.0f*z); v = (_Float16)(1.0f - 2.0f/(e + 1.0f));
            hv[r*4+3] = v; Bounce[row1][wv*32 + 16 + c16] = tagw | hbits(v);
        }
        __syncthreads();   // (D) all MFMA reads of Ah/Ain done; Bounce complete

        // ---- own strip -> Ah(t) ----
        {
            int g0 = c0 + c16, g1 = c0 + 16 + c16;
#pragma unroll
            for (int r = 0; r < 4; ++r) {
                int row0 = q*4 + r, row1 = 16 + row0;
                Ah[row0][(((g0 >> 3) + row0) & 63)*8 + (g0 & 7)] = hv[r*4+0];
                Ah[row0][(((g1 >> 3) + row0) & 63)*8 + (g1 & 7)] = hv[r*4+1];
                Ah[row1][(((g0 >> 3) + row1) & 63)*8 + (g0 & 7)] = hv[r*4+2];
                Ah[row1][(((g1 >> 3) + row1) & 63)*8 + (g1 & 7)] = hv[r*4+3];
            }
        }

        // ---- Bounce -> ring (coalesced, NO drain: sources pinned by next wait)
        {
            const uint4v* bp = (const uint4v*)&Bounce[0][0];
            sv0 = bp[4*tid + 0]; sv1 = bp[4*tid + 1];
            sv2 = bp[4*tid + 2]; sv3 = bp[4*tid + 3];
            const char* stb = hbuf + (size_t)((layer*8 + mg)*4 + (t & 3)) * SLOT_BYTES + bc0*4;
            if (fastp) { ST4("sc0"); } else { ST4("sc0 sc1"); }
        }
    }

    // drain final ring stores before endpgm
    asm volatile("s_waitcnt vmcnt(0)" :: "v"(sv0),"v"(sv1),"v"(sv2),"v"(sv3) : "memory");
}

// ---------------------------------------------------------------------------
// logits = h2(T-1) @ fc_w + fc_b ; out = sigmoid(logits). One wave per row.
// h2 stored as tagged dwords (payload in lo16). Dispatch-boundary cache
// writeback makes fast-path L2-resident ring data visible here.
__global__ void fc_kernel(const char* __restrict__ ws,
                          const float* __restrict__ fc_w,
                          const float* __restrict__ fc_b,
                          float* __restrict__ out)
{
    int row  = blockIdx.x;
    int lane = threadIdx.x;          // 64
    int m = row >> 5, lr = row & 31;
    const unsigned* h2 = (const unsigned*)(ws + HBUF_OFF
                         + (size_t)(((2*8 + m)*4 + 3)) * SLOT_BYTES)   // slot 511&3 = 3
                         + lr * UNIT;
    float s = 0.0f;
#pragma unroll
    for (int j = 0; j < 8; ++j) {
        unsigned d = h2[lane*8 + j];
        union { unsigned short u; _Float16 f; } x; x.u = (unsigned short)(d & 0xFFFFu);
        s += (float)x.f * fc_w[lane*8 + j];
    }
#pragma unroll
    for (int off = 32; off > 0; off >>= 1) s += __shfl_down(s, off);
    if (lane == 0) {
        float logit = s + fc_b[0];
        out[row] = 1.0f / (1.0f + __expf(-logit));
    }
}

// ---------------------------------------------------------------------------
extern "C" void kernel_launch(void* const* d_in, const int* in_sizes, int n_in,
                              void* d_out, int out_size, void* d_ws, size_t ws_size,
                              hipStream_t stream)
{
    const int*   tokens = (const int*)  d_in[0];
    const float* emb    = (const float*)d_in[1];
    const float* Wx0    = (const float*)d_in[2];
    const float* Wh0    = (const float*)d_in[3];
    const float* b0     = (const float*)d_in[4];
    const float* Wx1    = (const float*)d_in[5];
    const float* Wh1    = (const float*)d_in[6];
    const float* b1     = (const float*)d_in[7];
    const float* fcw    = (const float*)d_in[8];
    const float* fcb    = (const float*)d_in[9];
    char*  ws  = (char*)d_ws;
    float* out = (float*)d_out;

    // 1) flags = 0; ring prefilled with {tag=0xFFFF, payload=0} so t=0's
    //    sibling reads (expected tag (0-1)&0xFFFF) see valid h(-1)=0.
    int n16f = FLAGS_BYTES / 16;
    fill_ws_kernel<<<(n16f + 255)/256, 256, 0, stream>>>((uint4v*)ws, n16f, 0u);
    int n16r = HBUF_BYTES / 16;
    fill_ws_kernel<<<(n16r + 255)/256, 256, 0, stream>>>((uint4v*)(ws + HBUF_OFF), n16r, 0xFFFF0000u);

    // 2) pack weights fp32 -> fp16 B-fragment layout
    pack_w_kernel<<<(EMBD*UNIT + 255)/256, 256, 0, stream>>>(Wx0, (_Float16*)(ws + PWX0_OFF), EMBD, UNIT);
    pack_w_kernel<<<(UNIT*UNIT + 255)/256, 256, 0, stream>>>(Wh0, (_Float16*)(ws + PWH0_OFF), UNIT, UNIT);
    pack_w_kernel<<<(UNIT*UNIT + 255)/256, 256, 0, stream>>>(Wx1, (_Float16*)(ws + PWX1_OFF), UNIT, UNIT);
    pack_w_kernel<<<(UNIT*UNIT + 255)/256, 256, 0, stream>>>(Wh1, (_Float16*)(ws + PWH1_OFF), UNIT, UNIT);

    // 3) pipelined recurrence: 96 blocks, mgroup-per-XCD mapping
    rnn_main_kernel<<<96, 256, 0, stream>>>(tokens, emb, b0, b1, ws);

    // 4) final FC + sigmoid
    fc_kernel<<<256, 64, 0, stream>>>((const char*)ws, fcw, fcb, out);
}

// Round 8
// 2571.572 us; speedup vs baseline: 2.1880x; 2.1880x over previous
//
#include <hip/hip_runtime.h>

// ---------------------------------------------------------------------------
// 3-layer SimpleRNN, B=256 T=512 U=512 E=128, fp16 MFMA.
// R13 = R5's proven protocol with coherence scopes split by access pattern.
// ROOT CAUSE of R9-R12 hangs: sc0-only loads can be serviced by the CU's L1;
// a tid0 spin re-loading the SAME flag address never sees the remote update
// (nothing evicts the line during the spin) -> infinite stale spin. Flags
// must be device-scope (sc0 sc1). Bulk ring data is safe at sc0 in a
// colocated group (R8 proved: tag-validated fresh; each ring address re-read
// only every 4 steps with ~448KB streamed through 32KB L1 in between).
//  - Flags: ALWAYS sc0 sc1 (publish + poll) == R5 exactly.
//  - Ring data: sc0 when XCD handshake confirms colocation (per-XCD L2 is
//    the data path: ~3x cheaper RT, stores stop at L2), else sc0 sc1 (==R5).
// ---------------------------------------------------------------------------

#define BATCH 256
#define SEQ   512
#define EMBD  128
#define UNIT  512

typedef _Float16 half8 __attribute__((ext_vector_type(8)));
typedef _Float16 half4 __attribute__((ext_vector_type(4)));
typedef float    f32x4 __attribute__((ext_vector_type(4)));
typedef unsigned int uint4v __attribute__((ext_vector_type(4)));
typedef int      int4v __attribute__((ext_vector_type(4)));

// ws layout (bytes). Total ~4.63 MB. (R5 layout: fp16 ring, no tags.)
#define FLAGS_BYTES 4096
#define HBUF_OFF    4096
#define HBUF_ELEMS  (3*8*4*32*512)          // [layer][mgroup][slot][32][512] f16
#define HBUF_BYTES  (HBUF_ELEMS*2)
#define PWX0_OFF    (HBUF_OFF + HBUF_BYTES)
#define PWH0_OFF    (PWX0_OFF + EMBD*UNIT*2)
#define PWX1_OFF    (PWH0_OFF + UNIT*UNIT*2)
#define PWH1_OFF    (PWX1_OFF + UNIT*UNIT*2)

// ---------------------------------------------------------------------------
// FLAG ops: ALWAYS device-scope sc0 sc1 (L1-bypassing; spin-poll safe).
__device__ __forceinline__ void sc_st_int(int* p, int v) {
    asm volatile("global_store_dword %0, %1, off sc0 sc1" :: "v"(p), "v"(v) : "memory");
}

// three flag quads in one round trip (combined issue+wait: sound)
__device__ __forceinline__ void sc_ld_q3(const int* p0, const int* p1, const int* p2,
                                         int4v& a, int4v& b, int4v& c) {
    asm volatile(
        "global_load_dwordx4 %0, %3, off sc0 sc1\n\t"
        "global_load_dwordx4 %1, %4, off sc0 sc1\n\t"
        "global_load_dwordx4 %2, %5, off sc0 sc1\n\t"
        "s_waitcnt vmcnt(0)"
        : "=&v"(a), "=&v"(b), "=&v"(c)
        : "v"(p0), "v"(p1), "v"(p2)
        : "memory");
}

// DATA ops: sc0 when colocated (per-XCD L2 path), sc0 sc1 otherwise.
// 14 loads (6 Ah + 8 Ain) + single wait, one round trip, one asm block
__device__ __forceinline__ void sc_load14(
    const uint4v* a0, const uint4v* a1, const uint4v* a2,
    const uint4v* a3, const uint4v* a4, const uint4v* a5,
    const uint4v* b0, const uint4v* b1, const uint4v* b2, const uint4v* b3,
    const uint4v* b4, const uint4v* b5, const uint4v* b6, const uint4v* b7,
    uint4v& s0, uint4v& s1, uint4v& s2, uint4v& s3, uint4v& s4, uint4v& s5,
    uint4v& r0, uint4v& r1, uint4v& r2, uint4v& r3,
    uint4v& r4, uint4v& r5, uint4v& r6, uint4v& r7, bool fast)
{
    if (fast)
        asm volatile(
            "global_load_dwordx4 %0, %14, off sc0\n\t"
            "global_load_dwordx4 %1, %15, off sc0\n\t"
            "global_load_dwordx4 %2, %16, off sc0\n\t"
            "global_load_dwordx4 %3, %17, off sc0\n\t"
            "global_load_dwordx4 %4, %18, off sc0\n\t"
            "global_load_dwordx4 %5, %19, off sc0\n\t"
            "global_load_dwordx4 %6, %20, off sc0\n\t"
            "global_load_dwordx4 %7, %21, off sc0\n\t"
            "global_load_dwordx4 %8, %22, off sc0\n\t"
            "global_load_dwordx4 %9, %23, off sc0\n\t"
            "global_load_dwordx4 %10, %24, off sc0\n\t"
            "global_load_dwordx4 %11, %25, off sc0\n\t"
            "global_load_dwordx4 %12, %26, off sc0\n\t"
            "global_load_dwordx4 %13, %27, off sc0\n\t"
            "s_waitcnt vmcnt(0)"
            : "=&v"(s0), "=&v"(s1), "=&v"(s2), "=&v"(s3), "=&v"(s4), "=&v"(s5),
              "=&v"(r0), "=&v"(r1), "=&v"(r2), "=&v"(r3),
              "=&v"(r4), "=&v"(r5), "=&v"(r6), "=&v"(r7)
            : "v"(a0), "v"(a1), "v"(a2), "v"(a3), "v"(a4), "v"(a5),
              "v"(b0), "v"(b1), "v"(b2), "v"(b3), "v"(b4), "v"(b5), "v"(b6), "v"(b7)
            : "memory");
    else
        asm volatile(
            "global_load_dwordx4 %0, %14, off sc0 sc1\n\t"
            "global_load_dwordx4 %1, %15, off sc0 sc1\n\t"
            "global_load_dwordx4 %2, %16, off sc0 sc1\n\t"
            "global_load_dwordx4 %3, %17, off sc0 sc1\n\t"
            "global_load_dwordx4 %4, %18, off sc0 sc1\n\t"
            "global_load_dwordx4 %5, %19, off sc0 sc1\n\t"
            "global_load_dwordx4 %6, %20, off sc0 sc1\n\t"
            "global_load_dwordx4 %7, %21, off sc0 sc1\n\t"
            "global_load_dwordx4 %8, %22, off sc0 sc1\n\t"
            "global_load_dwordx4 %9, %23, off sc0 sc1\n\t"
            "global_load_dwordx4 %10, %24, off sc0 sc1\n\t"
            "global_load_dwordx4 %11, %25, off sc0 sc1\n\t"
            "global_load_dwordx4 %12, %26, off sc0 sc1\n\t"
            "global_load_dwordx4 %13, %27, off sc0 sc1\n\t"
            "s_waitcnt vmcnt(0)"
            : "=&v"(s0), "=&v"(s1), "=&v"(s2), "=&v"(s3), "=&v"(s4), "=&v"(s5),
              "=&v"(r0), "=&v"(r1), "=&v"(r2), "=&v"(r3),
              "=&v"(r4), "=&v"(r5), "=&v"(r6), "=&v"(r7)
            : "v"(a0), "v"(a1), "v"(a2), "v"(a3), "v"(a4), "v"(a5),
              "v"(b0), "v"(b1), "v"(b2), "v"(b3), "v"(b4), "v"(b5), "v"(b6), "v"(b7)
            : "memory");
}

__device__ __forceinline__ void sc_load6(
    const uint4v* p0, const uint4v* p1, const uint4v* p2,
    const uint4v* p3, const uint4v* p4, const uint4v* p5,
    uint4v& r0, uint4v& r1, uint4v& r2, uint4v& r3, uint4v& r4, uint4v& r5,
    bool fast)
{
    if (fast)
        asm volatile(
            "global_load_dwordx4 %0, %6, off sc0\n\t"
            "global_load_dwordx4 %1, %7, off sc0\n\t"
            "global_load_dwordx4 %2, %8, off sc0\n\t"
            "global_load_dwordx4 %3, %9, off sc0\n\t"
            "global_load_dwordx4 %4, %10, off sc0\n\t"
            "global_load_dwordx4 %5, %11, off sc0\n\t"
            "s_waitcnt vmcnt(0)"
            : "=&v"(r0), "=&v"(r1), "=&v"(r2), "=&v"(r3), "=&v"(r4), "=&v"(r5)
            : "v"(p0), "v"(p1), "v"(p2), "v"(p3), "v"(p4), "v"(p5)
            : "memory");
    else
        asm volatile(
            "global_load_dwordx4 %0, %6, off sc0 sc1\n\t"
            "global_load_dwordx4 %1, %7, off sc0 sc1\n\t"
            "global_load_dwordx4 %2, %8, off sc0 sc1\n\t"
            "global_load_dwordx4 %3, %9, off sc0 sc1\n\t"
            "global_load_dwordx4 %4, %10, off sc0 sc1\n\t"
            "global_load_dwordx4 %5, %11, off sc0 sc1\n\t"
            "s_waitcnt vmcnt(0)"
            : "=&v"(r0), "=&v"(r1), "=&v"(r2), "=&v"(r3), "=&v"(r4), "=&v"(r5)
            : "v"(p0), "v"(p1), "v"(p2), "v"(p3), "v"(p4), "v"(p5)
            : "memory");
}

__device__ __forceinline__ void sc_store2(uint4v* p0, uint4v v0, uint4v* p1, uint4v v1,
                                          bool fast) {
    if (fast)
        asm volatile(
            "global_store_dwordx4 %0, %2, off sc0\n\t"
            "global_store_dwordx4 %1, %3, off sc0\n\t"
            "s_waitcnt vmcnt(0)"
            :: "v"(p0), "v"(p1), "v"(v0), "v"(v1)
            : "memory");
    else
        asm volatile(
            "global_store_dwordx4 %0, %2, off sc0 sc1\n\t"
            "global_store_dwordx4 %1, %3, off sc0 sc1\n\t"
            "s_waitcnt vmcnt(0)"
            :: "v"(p0), "v"(p1), "v"(v0), "v"(v1)
            : "memory");
}

// ---------------------------------------------------------------------------
__global__ void zero_ws_kernel(uint4v* __restrict__ p, int n16) {
    int i = blockIdx.x * 256 + threadIdx.x;
    uint4v z = {0u, 0u, 0u, 0u};
    if (i < n16) p[i] = z;
}

// Pack fp32 weight [K][N] into MFMA B-fragment order, fp16:
// dst[((nt*KT + kt)*64 + lane)*8 + j] = W[kt*32 + (lane>>4)*8 + j][nt*16 + (lane&15)]
__global__ void pack_w_kernel(const float* __restrict__ src, _Float16* __restrict__ dst,
                              int K, int N) {
    int idx = blockIdx.x * 256 + threadIdx.x;
    if (idx >= K * N) return;
    int j    = idx & 7;
    int lane = (idx >> 3) & 63;
    int rest = idx >> 9;
    int KT   = K >> 5;
    int kt   = rest % KT;
    int nt   = rest / KT;
    int k = kt*32 + (lane >> 4)*8 + j;
    int n = nt*16 + (lane & 15);
    dst[idx] = (_Float16)src[k * N + n];
}

// ---------------------------------------------------------------------------
__global__ __launch_bounds__(256, 1)
void rnn_main_kernel(const int*   __restrict__ tokens,
                     const float* __restrict__ emb,
                     const float* __restrict__ b0,
                     const float* __restrict__ b1,
                     char* ws)
{
    const int bid   = blockIdx.x;
    const int mg    = bid & 7;           // batch group -> XCD under round-robin
    const int inner = bid >> 3;          // 0..11
    const int layer = inner >> 2;        // 0..2
    const int ns    = inner & 3;         // N-strip (128 cols)
    const int tid   = threadIdx.x;
    const int wv    = tid >> 6;
    const int lane  = tid & 63;
    const int q     = lane >> 4;         // quad
    const int c16   = lane & 15;

    int* flags = (int*)ws;               // quad per (layer,mg), 128B apart
    int* qOwn  = flags + (layer*8 + mg)*32;
    int* qUp   = flags + ((layer > 0 ? layer-1 : layer)*8 + mg)*32;
    int* qDn   = flags + ((layer < 2 ? layer+1 : layer)*8 + mg)*32;
    int* xslots = flags + 768;           // 96 ints: per-block XCD id + 1

    _Float16* hbuf = (_Float16*)(ws + HBUF_OFF);
    const _Float16* pWh = (const _Float16*)(ws + (layer == 0 ? PWH0_OFF : PWH1_OFF));
    const _Float16* pWx = (const _Float16*)(ws + (layer == 0 ? PWX0_OFF : PWX1_OFF));
    const float* bias = (layer == 0) ? b0 : b1;

    const int c0  = ns*128 + wv*32;      // global col base of this wave
    const int nt0 = c0 >> 4;

    // LDS 72KB. Rows swizzled by 16B-chunk rotation (chunk' = (chunk+row)&63).
    __shared__ _Float16 Ah [32][512];    // h_l(t-1) A-tile
    __shared__ _Float16 Ain[32][512];    // input A-tile (x_t or h_{l-1}(t))
    __shared__ _Float16 Bounce[32][128]; // epilogue store-coalescing bounce
    __shared__ int fastsh;

    // ---- XCD colocation handshake (tid 0): publish id, check 12 group members.
    // sc0 sc1 throughout (device scope, L1-bypassing -> spin-safe).
    // Terminates: all 96 blocks co-resident and publish before polling.
    if (tid == 0) {
        unsigned xcc;
        asm volatile("s_getreg_b32 %0, hwreg(HW_REG_XCC_ID)" : "=s"(xcc));
        sc_st_int(xslots + bid, (int)(xcc & 0xFu) + 1);
        int id0 = 0; bool same = true;
        for (int i = 0; i < 12; ++i) {
            int v;
            for (;;) {
                asm volatile("global_load_dword %0, %1, off sc0 sc1\n\ts_waitcnt vmcnt(0)"
                             : "=v"(v) : "v"(xslots + (mg + 8*i)) : "memory");
                if (v != 0) break;
                __builtin_amdgcn_s_sleep(1);
            }
            if (i == 0) id0 = v; else same = same && (v == id0);
        }
        fastsh = same ? 1 : 0;
    }

    // zero Ah: h(-1) = 0 (own strip; siblings come from zeroed ring at t=0)
    {
        uint4v z = {0u,0u,0u,0u};
#pragma unroll
        for (int i = 0; i < 8; ++i) ((uint4v*)Ah)[i*256 + tid] = z;
    }

    // ---- register-resident weights (B-fragments) ----
    half8 whf[16][2];
    half8 wxf[16][2];
#pragma unroll
    for (int kt = 0; kt < 16; ++kt)
#pragma unroll
        for (int n = 0; n < 2; ++n)
            whf[kt][n] = *(const half8*)&pWh[(((nt0 + n)*16 + kt)*64 + lane) * 8];
    if (layer == 0) {
#pragma unroll
        for (int kt = 0; kt < 4; ++kt)
#pragma unroll
            for (int n = 0; n < 2; ++n)
                wxf[kt][n] = *(const half8*)&pWx[(((nt0 + n)*4 + kt)*64 + lane) * 8];
    } else {
#pragma unroll
        for (int kt = 0; kt < 16; ++kt)
#pragma unroll
            for (int n = 0; n < 2; ++n)
                wxf[kt][n] = *(const half8*)&pWx[(((nt0 + n)*16 + kt)*64 + lane) * 8];
    }

    const float bv0 = bias[c0 + c16];
    const float bv1 = bias[c0 + 16 + c16];

    const int m0       = mg * 32;
    const int slotBase = (layer*8 + mg) * 4;

    // sibling strip ids (the 3 strips != ns, ascending)
    const int sA = (ns == 0) ? 1 : 0;
    const int sB = (ns <= 1) ? 2 : 1;
    const int sC = (ns <= 2) ? 3 : 2;

    __syncthreads();                     // fastsh visible to all threads
    const bool fastp = (fastsh != 0);

    for (int t = 0; t < SEQ; ++t) {
        // ---- poll (1 RT, sc0 sc1): own >= t, up >= t+1, down >= t-3 ----
        if (tid == 0) {
            for (;;) {
                int4v o, u, d;
                sc_ld_q3(qOwn, qUp, qDn, o, u, d);
                int mo = o[0] < o[1] ? o[0] : o[1];
                mo = mo < o[2] ? mo : o[2]; mo = mo < o[3] ? mo : o[3];
                int mu = u[0] < u[1] ? u[0] : u[1];
                mu = mu < u[2] ? mu : u[2]; mu = mu < u[3] ? mu : u[3];
                int md = d[0] < d[1] ? d[0] : d[1];
                md = md < d[2] ? md : d[2]; md = md < d[3] ? md : d[3];
                bool ok = (mo >= t);
                if (layer > 0)            ok = ok && (mu >= t + 1);
                if (layer < 2 && t >= 4)  ok = ok && (md >= t - 3);
                if (ok) break;
                __builtin_amdgcn_s_sleep(1);
            }
        }
        __syncthreads();   // (B) all deps satisfied

        // ---- chunk addressing ----
        const uint4v* tp = (const uint4v*)(hbuf + (slotBase + ((t + 3) & 3)) * 16384);
        const int j0 = 2*tid, j1 = j0 + 1;
        const int r0i = j0 >> 4, cl0 = j0 & 15;
        const int r1i = j1 >> 4, cl1 = j1 & 15;
        const int ccA0 = sA*16 + cl0, ccA1 = sA*16 + cl1;
        const int ccB0 = sB*16 + cl0, ccB1 = sB*16 + cl1;
        const int ccC0 = sC*16 + cl0, ccC1 = sC*16 + cl1;

        f32x4 acc00 = {0,0,0,0}, acc01 = {0,0,0,0}, acc10 = {0,0,0,0}, acc11 = {0,0,0,0};

        if (layer > 0) {
            const uint4v* sb = (const uint4v*)
                (hbuf + (((layer-1)*8 + mg)*4 + (t & 3)) * 16384);
            uint4v s0,s1,s2,s3,s4,s5, rr0,rr1,rr2,rr3,rr4,rr5,rr6,rr7;
            sc_load14(tp + r0i*64 + ccA0, tp + r1i*64 + ccA1,
                      tp + r0i*64 + ccB0, tp + r1i*64 + ccB1,
                      tp + r0i*64 + ccC0, tp + r1i*64 + ccC1,
                      sb +        tid, sb +  256 + tid, sb +  512 + tid, sb +  768 + tid,
                      sb + 1024 + tid, sb + 1280 + tid, sb + 1536 + tid, sb + 1792 + tid,
                      s0, s1, s2, s3, s4, s5,
                      rr0, rr1, rr2, rr3, rr4, rr5, rr6, rr7, fastp);
            *(uint4v*)&Ah[r0i][((ccA0 + r0i) & 63) * 8] = s0;
            *(uint4v*)&Ah[r1i][((ccA1 + r1i) & 63) * 8] = s1;
            *(uint4v*)&Ah[r0i][((ccB0 + r0i) & 63) * 8] = s2;
            *(uint4v*)&Ah[r1i][((ccB1 + r1i) & 63) * 8] = s3;
            *(uint4v*)&Ah[r0i][((ccC0 + r0i) & 63) * 8] = s4;
            *(uint4v*)&Ah[r1i][((ccC1 + r1i) & 63) * 8] = s5;
#pragma unroll
            for (int i = 0; i < 8; ++i) {
                uint4v v = (i==0)?rr0:(i==1)?rr1:(i==2)?rr2:(i==3)?rr3:
                           (i==4)?rr4:(i==5)?rr5:(i==6)?rr6:rr7;
                int ci = i*256 + tid;
                int r  = ci >> 6;
                int cc = ci & 63;
                *(uint4v*)&Ain[r][((cc + r) & 63) * 8] = v;
            }
            __syncthreads();   // (C) Ah + Ain ready

#pragma unroll
            for (int kt = 0; kt < 16; ++kt) {
                half8 a0 = *(const half8*)&Ah[c16]     [((kt*4 + q + c16)      & 63) * 8];
                half8 a1 = *(const half8*)&Ah[16 + c16][((kt*4 + q + 16 + c16) & 63) * 8];
                acc00 = __builtin_amdgcn_mfma_f32_16x16x32_f16(a0, whf[kt][0], acc00, 0, 0, 0);
                acc01 = __builtin_amdgcn_mfma_f32_16x16x32_f16(a0, whf[kt][1], acc01, 0, 0, 0);
                acc10 = __builtin_amdgcn_mfma_f32_16x16x32_f16(a1, whf[kt][0], acc10, 0, 0, 0);
                acc11 = __builtin_amdgcn_mfma_f32_16x16x32_f16(a1, whf[kt][1], acc11, 0, 0, 0);
            }
#pragma unroll
            for (int kt = 0; kt < 16; ++kt) {
                half8 a0 = *(const half8*)&Ain[c16]     [((kt*4 + q + c16)      & 63) * 8];
                half8 a1 = *(const half8*)&Ain[16 + c16][((kt*4 + q + 16 + c16) & 63) * 8];
                acc00 = __builtin_amdgcn_mfma_f32_16x16x32_f16(a0, wxf[kt][0], acc00, 0, 0, 0);
                acc01 = __builtin_amdgcn_mfma_f32_16x16x32_f16(a0, wxf[kt][1], acc01, 0, 0, 0);
                acc10 = __builtin_amdgcn_mfma_f32_16x16x32_f16(a1, wxf[kt][0], acc10, 0, 0, 0);
                acc11 = __builtin_amdgcn_mfma_f32_16x16x32_f16(a1, wxf[kt][1], acc11, 0, 0, 0);
            }
        } else {
            // layer 0: sibling Ah loads + embedding gather (plain cached loads)
            uint4v s0, s1, s2, s3, s4, s5;
            sc_load6(tp + r0i*64 + ccA0, tp + r1i*64 + ccA1,
                     tp + r0i*64 + ccB0, tp + r1i*64 + ccB1,
                     tp + r0i*64 + ccC0, tp + r1i*64 + ccC1,
                     s0, s1, s2, s3, s4, s5, fastp);
            *(uint4v*)&Ah[r0i][((ccA0 + r0i) & 63) * 8] = s0;
            *(uint4v*)&Ah[r1i][((ccA1 + r1i) & 63) * 8] = s1;
            *(uint4v*)&Ah[r0i][((ccB0 + r0i) & 63) * 8] = s2;
            *(uint4v*)&Ah[r1i][((ccB1 + r1i) & 63) * 8] = s3;
            *(uint4v*)&Ah[r0i][((ccC0 + r0i) & 63) * 8] = s4;
            *(uint4v*)&Ah[r1i][((ccC1 + r1i) & 63) * 8] = s5;
#pragma unroll
            for (int i = 0; i < 4; ++i) {
                int idx = i*256 + tid;           // 1024 float4 chunks (32 rows x 32)
                int r   = idx >> 5;
                int qq  = idx & 31;
                int tok = tokens[(m0 + r)*SEQ + t];
                float4 f = *((const float4*)(emb + (long)tok * EMBD) + qq);
                half4 h = { (_Float16)f.x, (_Float16)f.y, (_Float16)f.z, (_Float16)f.w };
                *(half4*)&Ain[r][((((qq >> 1) + r) & 63) * 8) + (qq & 1) * 4] = h;
            }
            __syncthreads();   // (C) Ah + Ain ready

#pragma unroll
            for (int kt = 0; kt < 16; ++kt) {
                half8 a0 = *(const half8*)&Ah[c16]     [((kt*4 + q + c16)      & 63) * 8];
                half8 a1 = *(const half8*)&Ah[16 + c16][((kt*4 + q + 16 + c16) & 63) * 8];
                acc00 = __builtin_amdgcn_mfma_f32_16x16x32_f16(a0, whf[kt][0], acc00, 0, 0, 0);
                acc01 = __builtin_amdgcn_mfma_f32_16x16x32_f16(a0, whf[kt][1], acc01, 0, 0, 0);
                acc10 = __builtin_amdgcn_mfma_f32_16x16x32_f16(a1, whf[kt][0], acc10, 0, 0, 0);
                acc11 = __builtin_amdgcn_mfma_f32_16x16x32_f16(a1, whf[kt][1], acc11, 0, 0, 0);
            }
#pragma unroll
            for (int kt = 0; kt < 4; ++kt) {
                half8 a0 = *(const half8*)&Ain[c16]     [((kt*4 + q + c16)      & 63) * 8];
                half8 a1 = *(const half8*)&Ain[16 + c16][((kt*4 + q + 16 + c16) & 63) * 8];
                acc00 = __builtin_amdgcn_mfma_f32_16x16x32_f16(a0, wxf[kt][0], acc00, 0, 0, 0);
                acc01 = __builtin_amdgcn_mfma_f32_16x16x32_f16(a0, wxf[kt][1], acc01, 0, 0, 0);
                acc10 = __builtin_amdgcn_mfma_f32_16x16x32_f16(a1, wxf[kt][0], acc10, 0, 0, 0);
                acc11 = __builtin_amdgcn_mfma_f32_16x16x32_f16(a1, wxf[kt][1], acc11, 0, 0, 0);
            }
        }

        // ---- tanh -> hv regs + Bounce (disjoint per-wave, no barrier needed) ----
        _Float16 hv[16];
#pragma unroll
        for (int r = 0; r < 4; ++r) {
            int row0 = q*4 + r, row1 = 16 + row0;
            float z, e; _Float16 v;
            z = acc00[r] + bv0; e = __expf(2.0f*z); v = (_Float16)(1.0f - 2.0f/(e + 1.0f));
            hv[r*4+0] = v; Bounce[row0][wv*32 + c16]      = v;
            z = acc01[r] + bv1; e = __expf(2.0f*z); v = (_Float16)(1.0f - 2.0f/(e + 1.0f));
            hv[r*4+1] = v; Bounce[row0][wv*32 + 16 + c16] = v;
            z = acc10[r] + bv0; e = __expf(2.0f*z); v = (_Float16)(1.0f - 2.0f/(e + 1.0f));
            hv[r*4+2] = v; Bounce[row1][wv*32 + c16]      = v;
            z = acc11[r] + bv1; e = __expf(2.0f*z); v = (_Float16)(1.0f - 2.0f/(e + 1.0f));
            hv[r*4+3] = v; Bounce[row1][wv*32 + 16 + c16] = v;
        }
        __syncthreads();   // (D) Ah/Ain reads done by all waves; Bounce complete

        // ---- own strip -> Ah(t); Bounce -> ring (coalesced, per-lane drain) ----
        {
            int g0 = c0 + c16, g1 = c0 + 16 + c16;
#pragma unroll
            for (int r = 0; r < 4; ++r) {
                int row0 = q*4 + r, row1 = 16 + row0;
                Ah[row0][(((g0 >> 3) + row0) & 63)*8 + (g0 & 7)] = hv[r*4+0];
                Ah[row0][(((g1 >> 3) + row0) & 63)*8 + (g1 & 7)] = hv[r*4+1];
                Ah[row1][(((g0 >> 3) + row1) & 63)*8 + (g0 & 7)] = hv[r*4+2];
                Ah[row1][(((g1 >> 3) + row1) & 63)*8 + (g1 & 7)] = hv[r*4+3];
            }
            _Float16* tc = hbuf + (slotBase + (t & 3)) * 16384;
            uint4v v0 = ((const uint4v*)Bounce)[j0];
            uint4v v1 = ((const uint4v*)Bounce)[j1];
            uint4v* d0 = (uint4v*)(tc + (j0 >> 4)*512 + ns*128) + (j0 & 15);
            uint4v* d1 = (uint4v*)(tc + (j1 >> 4)*512 + ns*128) + (j1 & 15);
            sc_store2(d0, v0, d1, v1, fastp);
        }
        __syncthreads();   // (E) all lanes drained; Ah(t) complete
        if (tid == 0) sc_st_int(qOwn + ns, t + 1);   // flag publish: sc0 sc1
    }
}

// ---------------------------------------------------------------------------
// logits = h2(T-1) @ fc_w + fc_b ; out = sigmoid(logits). One wave per row.
// Dispatch-boundary writeback makes fast-path L2-resident ring visible (R8).
__global__ void fc_kernel(const char* __restrict__ ws,
                          const float* __restrict__ fc_w,
                          const float* __restrict__ fc_b,
                          float* __restrict__ out)
{
    int row  = blockIdx.x;
    int lane = threadIdx.x;          // 64
    int m = row >> 5, lr = row & 31;
    const _Float16* h2 = (const _Float16*)(ws + HBUF_OFF)
                         + (((2*8 + m)*4 + 3) * 16384)   // slot 511&3 = 3
                         + lr * UNIT;
    half8 hv = *(const half8*)&h2[lane * 8];
    const float* w = fc_w + lane * 8;
    float s = 0.0f;
#pragma unroll
    for (int j = 0; j < 8; ++j) s += (float)hv[j] * w[j];
#pragma unroll
    for (int off = 32; off > 0; off >>= 1) s += __shfl_down(s, off);
    if (lane == 0) {
        float logit = s + fc_b[0];
        out[row] = 1.0f / (1.0f + __expf(-logit));
    }
}

// ---------------------------------------------------------------------------
extern "C" void kernel_launch(void* const* d_in, const int* in_sizes, int n_in,
                              void* d_out, int out_size, void* d_ws, size_t ws_size,
                              hipStream_t stream)
{
    const int*   tokens = (const int*)  d_in[0];
    const float* emb    = (const float*)d_in[1];
    const float* Wx0    = (const float*)d_in[2];
    const float* Wh0    = (const float*)d_in[3];
    const float* b0     = (const float*)d_in[4];
    const float* Wx1    = (const float*)d_in[5];
    const float* Wh1    = (const float*)d_in[6];
    const float* b1     = (const float*)d_in[7];
    const float* fcw    = (const float*)d_in[8];
    const float* fcb    = (const float*)d_in[9];
    char*  ws  = (char*)d_ws;
    float* out = (float*)d_out;

    // 1) zero flags + h ring (t=0 reads ring slot 3 as h(-1)=0)
    int n16 = (FLAGS_BYTES + HBUF_BYTES) / 16;
    zero_ws_kernel<<<(n16 + 255)/256, 256, 0, stream>>>((uint4v*)ws, n16);

    // 2) pack weights fp32 -> fp16 B-fragment layout
    pack_w_kernel<<<(EMBD*UNIT + 255)/256, 256, 0, stream>>>(Wx0, (_Float16*)(ws + PWX0_OFF), EMBD, UNIT);
    pack_w_kernel<<<(UNIT*UNIT + 255)/256, 256, 0, stream>>>(Wh0, (_Float16*)(ws + PWH0_OFF), UNIT, UNIT);
    pack_w_kernel<<<(UNIT*UNIT + 255)/256, 256, 0, stream>>>(Wx1, (_Float16*)(ws + PWX1_OFF), UNIT, UNIT);
    pack_w_kernel<<<(UNIT*UNIT + 255)/256, 256, 0, stream>>>(Wh1, (_Float16*)(ws + PWH1_OFF), UNIT, UNIT);

    // 3) pipelined recurrence: 96 blocks, mgroup-per-XCD mapping
    rnn_main_kernel<<<96, 256, 0, stream>>>(tokens, emb, b0, b1, ws);

    // 4) final FC + sigmoid
    fc_kernel<<<256, 64, 0, stream>>>((const char*)ws, fcw, fcb, out);
}